// Round 3
// baseline (90.772 us; speedup 1.0000x reference)
//
#include <hip/hip_runtime.h>

#define C_CH 128
typedef __attribute__((ext_vector_type(8))) _Float16 half8;

// ---- fused transpose + fp32->fp16: [N][C][HW] -> [N][HW][C], both levels
// packed into one buffer: lev0 at 0, lev1 at 6*2816*128 elements.
__global__ __launch_bounds__(256) void transpose_both_f16(
    const float* __restrict__ f0, const float* __restrict__ f1,
    _Float16* __restrict__ o) {
  __shared__ float tile[32][33];
  int n = blockIdx.z;
  int lev = (blockIdx.x >= 88) ? 1 : 0;
  int xt = lev ? (blockIdx.x - 88) : blockIdx.x;
  int HW = lev ? 704 : 2816;
  const float* src = (lev ? f1 : f0) + (size_t)n * C_CH * HW;
  _Float16* dst = o + (lev ? (size_t)6 * C_CH * 2816 + (size_t)n * C_CH * 704
                           : (size_t)n * C_CH * 2816);
  int hw0 = xt * 32;
  int c0  = blockIdx.y * 32;
  #pragma unroll
  for (int i = threadIdx.y; i < 32; i += 8) {
    int hw = hw0 + threadIdx.x;
    if (hw < HW) tile[i][threadIdx.x] = src[(size_t)(c0 + i) * HW + hw];
  }
  __syncthreads();
  #pragma unroll
  for (int i = threadIdx.y; i < 32; i += 8) {
    int hw = hw0 + i;
    if (hw < HW)
      dst[(size_t)hw * C_CH + c0 + threadIdx.x] = (_Float16)tile[threadIdx.x][i];
  }
}

// ---- main: Phase A (96 threads) computes taps once per (pt,cam) into LDS;
// Phase B: 16 lanes/point, 8 fp16 channels/lane (one dwordx4 per tap).
__global__ __launch_bounds__(256) void bev_main_f16(
    const float* __restrict__ rp,   // [4][128][128][3]
    const _Float16* __restrict__ ft,// packed transposed feats
    const float* __restrict__ l2i,  // [6][4][4]
    float* __restrict__ out)        // [16384][4][128]
{
  __shared__ int   s_off[16][6][8];
  __shared__ float s_wt [16][6][8];
  __shared__ float s_flag[16][6];

  int tid = threadIdx.x;
  int pt0 = blockIdx.x * 16;

  if (tid < 96) {
    int lp = tid / 6;
    int n  = tid - lp * 6;
    int pt = pt0 + lp;
    int p = pt & 3, q = pt >> 2, h = q >> 7, w = q & 127;
    const float* rpp = rp + ((size_t)((p * 128 + h) * 128 + w)) * 3;
    float X = rpp[0] * 102.4f - 51.2f;
    float Y = rpp[1] * 102.4f - 51.2f;
    float Z = rpp[2] * 8.0f - 5.0f;
    const float* M = l2i + n * 16;
    float cx = fmaf(M[0], X, fmaf(M[1], Y, fmaf(M[2],  Z, M[3])));
    float cy = fmaf(M[4], X, fmaf(M[5], Y, fmaf(M[6],  Z, M[7])));
    float cz = fmaf(M[8], X, fmaf(M[9], Y, fmaf(M[10], Z, M[11])));
    float dz = fmaxf(cz, 1e-5f);
    float u = cx / (dz * 704.0f);
    float v = cy / (dz * 256.0f);
    bool m = (cz > 1e-5f) && (u > 0.0f) && (u < 1.0f) && (v > 0.0f) && (v < 1.0f);
    s_flag[lp][n] = m ? 1.0f : 0.0f;
    if (m) {
      float gx = u * 2.0f - 1.0f;
      float gy = v * 2.0f - 1.0f;
      #pragma unroll
      for (int lev = 0; lev < 2; ++lev) {
        const int H = lev ? 16 : 32, W = lev ? 44 : 88;
        const int base = lev ? (6 * 2816 * C_CH + n * 704 * C_CH)
                             : (n * 2816 * C_CH);
        float x = ((gx + 1.0f) * (float)W - 1.0f) * 0.5f;   // matches reference
        float y = ((gy + 1.0f) * (float)H - 1.0f) * 0.5f;
        float x0f = floorf(x), y0f = floorf(y);
        int x0 = (int)x0f, y0 = (int)y0f;
        int x1 = x0 + 1, y1 = y0 + 1;
        float wx1 = x - x0f, wx0 = 1.0f - wx1;
        float wy1 = y - y0f, wy0 = 1.0f - wy1;
        float vx0 = (x0 >= 0 && x0 < W) ? 1.f : 0.f;
        float vx1 = (x1 >= 0 && x1 < W) ? 1.f : 0.f;
        float vy0 = (y0 >= 0 && y0 < H) ? 1.f : 0.f;
        float vy1 = (y1 >= 0 && y1 < H) ? 1.f : 0.f;
        int cx0 = min(max(x0, 0), W - 1), cx1 = min(max(x1, 0), W - 1);
        int cy0 = min(max(y0, 0), H - 1), cy1 = min(max(y1, 0), H - 1);
        s_off[lp][n][lev * 4 + 0] = base + (cy0 * W + cx0) * C_CH;
        s_off[lp][n][lev * 4 + 1] = base + (cy0 * W + cx1) * C_CH;
        s_off[lp][n][lev * 4 + 2] = base + (cy1 * W + cx0) * C_CH;
        s_off[lp][n][lev * 4 + 3] = base + (cy1 * W + cx1) * C_CH;
        s_wt[lp][n][lev * 4 + 0] = wx0 * wy0 * vx0 * vy0;
        s_wt[lp][n][lev * 4 + 1] = wx1 * wy0 * vx1 * vy0;
        s_wt[lp][n][lev * 4 + 2] = wx0 * wy1 * vx0 * vy1;
        s_wt[lp][n][lev * 4 + 3] = wx1 * wy1 * vx1 * vy1;
      }
    }
  }
  __syncthreads();

  int lane = tid & 15;
  int grp  = tid >> 4;
  const _Float16* ftc = ft + (lane << 3);
  float acc[8] = {0.f, 0.f, 0.f, 0.f, 0.f, 0.f, 0.f, 0.f};
  float cnt = 0.f;
  #pragma unroll
  for (int n = 0; n < 6; ++n) {
    float flag = s_flag[grp][n];
    cnt += flag;
    if (flag != 0.0f) {
      #pragma unroll
      for (int t = 0; t < 8; ++t) {
        int off = s_off[grp][n][t];
        float wgt = s_wt[grp][n][t];
        half8 val = *reinterpret_cast<const half8*>(ftc + off);
        #pragma unroll
        for (int j = 0; j < 8; ++j)
          acc[j] = fmaf((float)val[j], wgt, acc[j]);
      }
    }
  }
  float s = 0.5f / fmaxf(cnt, 1.0f);
  int pt = pt0 + grp;
  float* op = out + (size_t)pt * C_CH + (lane << 3);
  *reinterpret_cast<float4*>(op) =
      make_float4(acc[0] * s, acc[1] * s, acc[2] * s, acc[3] * s);
  *reinterpret_cast<float4*>(op + 4) =
      make_float4(acc[4] * s, acc[5] * s, acc[6] * s, acc[7] * s);
}

// ---- fallback: native CHW fp32 gather (if ws too small) ----
__global__ __launch_bounds__(256) void bev_fallback(
    const float* __restrict__ rp, const float* __restrict__ f0,
    const float* __restrict__ f1, const float* __restrict__ l2i,
    float* __restrict__ out) {
  int lane = threadIdx.x & 31;
  int grp  = threadIdx.x >> 5;
  int pt   = blockIdx.x * 8 + grp;
  int p = pt & 3, q = pt >> 2, h = q >> 7, w = q & 127;
  int c = lane << 2;
  const float* rpp = rp + ((size_t)((p * 128 + h) * 128 + w)) * 3;
  float X = rpp[0] * 102.4f - 51.2f;
  float Y = rpp[1] * 102.4f - 51.2f;
  float Z = rpp[2] * 8.0f - 5.0f;
  float4 acc = make_float4(0.f, 0.f, 0.f, 0.f);
  float cnt = 0.0f;
  for (int n = 0; n < 6; ++n) {
    const float* M = l2i + n * 16;
    float cx = M[0] * X + M[1] * Y + M[2]  * Z + M[3];
    float cy = M[4] * X + M[5] * Y + M[6]  * Z + M[7];
    float cz = M[8] * X + M[9] * Y + M[10] * Z + M[11];
    float dz = fmaxf(cz, 1e-5f);
    float u = cx / (dz * 704.0f);
    float v = cy / (dz * 256.0f);
    if (!((cz > 1e-5f) && (u > 0.f) && (u < 1.f) && (v > 0.f) && (v < 1.f))) continue;
    cnt += 1.0f;
    float gx = u * 2.0f - 1.0f, gy = v * 2.0f - 1.0f;
    for (int lev = 0; lev < 2; ++lev) {
      const int H = lev ? 16 : 32, W = lev ? 44 : 88;
      const float* f = lev ? f1 : f0;
      size_t HW = (size_t)H * W;
      const float* b0 = f + (size_t)n * C_CH * HW + (size_t)c * HW;
      float x = ((gx + 1.0f) * (float)W - 1.0f) * 0.5f;
      float y = ((gy + 1.0f) * (float)H - 1.0f) * 0.5f;
      float x0f = floorf(x), y0f = floorf(y);
      int x0 = (int)x0f, y0 = (int)y0f, x1 = x0 + 1, y1 = y0 + 1;
      float wx1 = x - x0f, wx0 = 1.0f - wx1;
      float wy1 = y - y0f, wy0 = 1.0f - wy1;
      int xs[4] = {x0, x1, x0, x1}, ys[4] = {y0, y0, y1, y1};
      float ws4[4] = {wx0 * wy0, wx1 * wy0, wx0 * wy1, wx1 * wy1};
      for (int t = 0; t < 4; ++t) {
        if (xs[t] < 0 || xs[t] >= W || ys[t] < 0 || ys[t] >= H) continue;
        size_t off = (size_t)ys[t] * W + xs[t];
        float wgt = ws4[t];
        acc.x = fmaf(b0[off], wgt, acc.x);
        acc.y = fmaf(b0[HW + off], wgt, acc.y);
        acc.z = fmaf(b0[2 * HW + off], wgt, acc.z);
        acc.w = fmaf(b0[3 * HW + off], wgt, acc.w);
      }
    }
  }
  float s = 0.5f / fmaxf(cnt, 1.0f);
  *reinterpret_cast<float4*>(out + (size_t)pt * C_CH + c) =
      make_float4(acc.x * s, acc.y * s, acc.z * s, acc.w * s);
}

extern "C" void kernel_launch(void* const* d_in, const int* in_sizes, int n_in,
                              void* d_out, int out_size, void* d_ws, size_t ws_size,
                              hipStream_t stream) {
  const float* rp  = (const float*)d_in[0];
  const float* f0  = (const float*)d_in[1];
  const float* f1  = (const float*)d_in[2];
  const float* l2i = (const float*)d_in[3];
  float* out = (float*)d_out;

  const size_t n_elems = (size_t)6 * C_CH * 2816 + (size_t)6 * C_CH * 704;
  const size_t need = n_elems * sizeof(_Float16);

  if (ws_size >= need) {
    _Float16* ftp = (_Float16*)d_ws;
    transpose_both_f16<<<dim3(110, 4, 6), dim3(32, 8, 1), 0, stream>>>(f0, f1, ftp);
    bev_main_f16<<<dim3(4096), dim3(256), 0, stream>>>(rp, ftp, l2i, out);
  } else {
    bev_fallback<<<dim3(8192), dim3(256), 0, stream>>>(rp, f0, f1, l2i, out);
  }
}

// Round 4
// 88.530 us; speedup vs baseline: 1.0253x; 1.0253x over previous
//
#include <hip/hip_runtime.h>

#define C_CH 128
typedef __attribute__((ext_vector_type(8))) _Float16 half8;
typedef __attribute__((ext_vector_type(2))) _Float16 half2v;

// ---- fused transpose + fp32->fp16: [N][C][HW] -> [N][HW][C], both levels
// packed: lev0 at 0, lev1 at 6*2816*128 elements.
__global__ __launch_bounds__(256) void transpose_both_f16(
    const float* __restrict__ f0, const float* __restrict__ f1,
    _Float16* __restrict__ o) {
  __shared__ float tile[32][33];
  int n = blockIdx.z;
  int lev = (blockIdx.x >= 88) ? 1 : 0;
  int xt = lev ? (blockIdx.x - 88) : blockIdx.x;
  int HW = lev ? 704 : 2816;
  const float* src = (lev ? f1 : f0) + (size_t)n * C_CH * HW;
  _Float16* dst = o + (lev ? (size_t)6 * C_CH * 2816 + (size_t)n * C_CH * 704
                           : (size_t)n * C_CH * 2816);
  int hw0 = xt * 32;
  int c0  = blockIdx.y * 32;
  int tx = threadIdx.x, ty = threadIdx.y;
  #pragma unroll
  for (int i = ty; i < 32; i += 8) {
    int hw = hw0 + tx;
    if (hw < HW) tile[i][tx] = src[(size_t)(c0 + i) * HW + hw];
  }
  __syncthreads();
  // stores: each thread writes one half2 (channels 2j,2j+1) per row
  int j = tx & 15;   // channel-pair index
  int r = tx >> 4;   // row offset 0/1
  #pragma unroll
  for (int i2 = ty; i2 < 16; i2 += 8) {
    int row = i2 * 2 + r;
    int hw = hw0 + row;
    if (hw < HW) {
      half2v pr;
      pr.x = (_Float16)tile[2 * j][row];
      pr.y = (_Float16)tile[2 * j + 1][row];
      *reinterpret_cast<half2v*>(dst + (size_t)hw * C_CH + c0 + 2 * j) = pr;
    }
  }
}

// ---- main: Phase A computes taps for ACTIVE cams only (compacted via LDS
// atomicAdd); Phase B loops over the compacted list (avg ~0.75 cams/point
// instead of always 6). 16 lanes/point, 8 fp16 channels/lane.
__global__ __launch_bounds__(256) void bev_main_f16(
    const float* __restrict__ rp,   // [4][128][128][3]
    const _Float16* __restrict__ ft,// packed transposed feats
    const float* __restrict__ l2i,  // [6][4][4]
    float* __restrict__ out)        // [16384][4][128]
{
  __shared__ int   s_cnt[16];
  __shared__ int   s_off[16][6][8];
  __shared__ float s_wt [16][6][8];

  int tid = threadIdx.x;
  int pt0 = blockIdx.x * 16;

  if (tid < 16) s_cnt[tid] = 0;
  __syncthreads();

  if (tid < 96) {
    int lp = tid / 6;
    int n  = tid - lp * 6;
    int pt = pt0 + lp;
    int p = pt & 3, q = pt >> 2, h = q >> 7, w = q & 127;
    const float* rpp = rp + ((size_t)((p * 128 + h) * 128 + w)) * 3;
    float X = rpp[0] * 102.4f - 51.2f;
    float Y = rpp[1] * 102.4f - 51.2f;
    float Z = rpp[2] * 8.0f - 5.0f;
    const float* M = l2i + n * 16;
    float cx = fmaf(M[0], X, fmaf(M[1], Y, fmaf(M[2],  Z, M[3])));
    float cy = fmaf(M[4], X, fmaf(M[5], Y, fmaf(M[6],  Z, M[7])));
    float cz = fmaf(M[8], X, fmaf(M[9], Y, fmaf(M[10], Z, M[11])));
    float dz = fmaxf(cz, 1e-5f);
    float u = cx / (dz * 704.0f);
    float v = cy / (dz * 256.0f);
    bool m = (cz > 1e-5f) && (u > 0.0f) && (u < 1.0f) && (v > 0.0f) && (v < 1.0f);
    if (m) {
      int k = atomicAdd(&s_cnt[lp], 1);
      float gx = u * 2.0f - 1.0f;
      float gy = v * 2.0f - 1.0f;
      #pragma unroll
      for (int lev = 0; lev < 2; ++lev) {
        const int H = lev ? 16 : 32, W = lev ? 44 : 88;
        const int base = lev ? (6 * 2816 * C_CH + n * 704 * C_CH)
                             : (n * 2816 * C_CH);
        float x = ((gx + 1.0f) * (float)W - 1.0f) * 0.5f;   // matches reference
        float y = ((gy + 1.0f) * (float)H - 1.0f) * 0.5f;
        float x0f = floorf(x), y0f = floorf(y);
        int x0 = (int)x0f, y0 = (int)y0f;
        int x1 = x0 + 1, y1 = y0 + 1;
        float wx1 = x - x0f, wx0 = 1.0f - wx1;
        float wy1 = y - y0f, wy0 = 1.0f - wy1;
        float vx0 = (x0 >= 0 && x0 < W) ? 1.f : 0.f;
        float vx1 = (x1 >= 0 && x1 < W) ? 1.f : 0.f;
        float vy0 = (y0 >= 0 && y0 < H) ? 1.f : 0.f;
        float vy1 = (y1 >= 0 && y1 < H) ? 1.f : 0.f;
        int cx0 = min(max(x0, 0), W - 1), cx1 = min(max(x1, 0), W - 1);
        int cy0 = min(max(y0, 0), H - 1), cy1 = min(max(y1, 0), H - 1);
        s_off[lp][k][lev * 4 + 0] = base + (cy0 * W + cx0) * C_CH;
        s_off[lp][k][lev * 4 + 1] = base + (cy0 * W + cx1) * C_CH;
        s_off[lp][k][lev * 4 + 2] = base + (cy1 * W + cx0) * C_CH;
        s_off[lp][k][lev * 4 + 3] = base + (cy1 * W + cx1) * C_CH;
        s_wt[lp][k][lev * 4 + 0] = wx0 * wy0 * vx0 * vy0;
        s_wt[lp][k][lev * 4 + 1] = wx1 * wy0 * vx1 * vy0;
        s_wt[lp][k][lev * 4 + 2] = wx0 * wy1 * vx0 * vy1;
        s_wt[lp][k][lev * 4 + 3] = wx1 * wy1 * vx1 * vy1;
      }
    }
  }
  __syncthreads();

  int lane = tid & 15;
  int grp  = tid >> 4;
  const _Float16* ftc = ft + (lane << 3);
  float acc[8] = {0.f, 0.f, 0.f, 0.f, 0.f, 0.f, 0.f, 0.f};
  int cnt = s_cnt[grp];
  for (int k = 0; k < cnt; ++k) {
    #pragma unroll
    for (int t = 0; t < 8; ++t) {
      int off = s_off[grp][k][t];
      float wgt = s_wt[grp][k][t];
      half8 val = *reinterpret_cast<const half8*>(ftc + off);
      #pragma unroll
      for (int jj = 0; jj < 8; ++jj)
        acc[jj] = fmaf((float)val[jj], wgt, acc[jj]);
    }
  }
  float s = 0.5f / fmaxf((float)cnt, 1.0f);
  int pt = pt0 + grp;
  float* op = out + (size_t)pt * C_CH + (lane << 3);
  *reinterpret_cast<float4*>(op) =
      make_float4(acc[0] * s, acc[1] * s, acc[2] * s, acc[3] * s);
  *reinterpret_cast<float4*>(op + 4) =
      make_float4(acc[4] * s, acc[5] * s, acc[6] * s, acc[7] * s);
}

// ---- fallback: native CHW fp32 gather (if ws too small) ----
__global__ __launch_bounds__(256) void bev_fallback(
    const float* __restrict__ rp, const float* __restrict__ f0,
    const float* __restrict__ f1, const float* __restrict__ l2i,
    float* __restrict__ out) {
  int lane = threadIdx.x & 31;
  int grp  = threadIdx.x >> 5;
  int pt   = blockIdx.x * 8 + grp;
  int p = pt & 3, q = pt >> 2, h = q >> 7, w = q & 127;
  int c = lane << 2;
  const float* rpp = rp + ((size_t)((p * 128 + h) * 128 + w)) * 3;
  float X = rpp[0] * 102.4f - 51.2f;
  float Y = rpp[1] * 102.4f - 51.2f;
  float Z = rpp[2] * 8.0f - 5.0f;
  float4 acc = make_float4(0.f, 0.f, 0.f, 0.f);
  float cnt = 0.0f;
  for (int n = 0; n < 6; ++n) {
    const float* M = l2i + n * 16;
    float cx = M[0] * X + M[1] * Y + M[2]  * Z + M[3];
    float cy = M[4] * X + M[5] * Y + M[6]  * Z + M[7];
    float cz = M[8] * X + M[9] * Y + M[10] * Z + M[11];
    float dz = fmaxf(cz, 1e-5f);
    float u = cx / (dz * 704.0f);
    float v = cy / (dz * 256.0f);
    if (!((cz > 1e-5f) && (u > 0.f) && (u < 1.f) && (v > 0.f) && (v < 1.f))) continue;
    cnt += 1.0f;
    float gx = u * 2.0f - 1.0f, gy = v * 2.0f - 1.0f;
    for (int lev = 0; lev < 2; ++lev) {
      const int H = lev ? 16 : 32, W = lev ? 44 : 88;
      const float* f = lev ? f1 : f0;
      size_t HW = (size_t)H * W;
      const float* b0 = f + (size_t)n * C_CH * HW + (size_t)c * HW;
      float x = ((gx + 1.0f) * (float)W - 1.0f) * 0.5f;
      float y = ((gy + 1.0f) * (float)H - 1.0f) * 0.5f;
      float x0f = floorf(x), y0f = floorf(y);
      int x0 = (int)x0f, y0 = (int)y0f, x1 = x0 + 1, y1 = y0 + 1;
      float wx1 = x - x0f, wx0 = 1.0f - wx1;
      float wy1 = y - y0f, wy0 = 1.0f - wy1;
      int xs[4] = {x0, x1, x0, x1}, ys[4] = {y0, y0, y1, y1};
      float ws4[4] = {wx0 * wy0, wx1 * wy0, wx0 * wy1, wx1 * wy1};
      for (int t = 0; t < 4; ++t) {
        if (xs[t] < 0 || xs[t] >= W || ys[t] < 0 || ys[t] >= H) continue;
        size_t off = (size_t)ys[t] * W + xs[t];
        float wgt = ws4[t];
        acc.x = fmaf(b0[off], wgt, acc.x);
        acc.y = fmaf(b0[HW + off], wgt, acc.y);
        acc.z = fmaf(b0[2 * HW + off], wgt, acc.z);
        acc.w = fmaf(b0[3 * HW + off], wgt, acc.w);
      }
    }
  }
  float s = 0.5f / fmaxf(cnt, 1.0f);
  *reinterpret_cast<float4*>(out + (size_t)pt * C_CH + c) =
      make_float4(acc.x * s, acc.y * s, acc.z * s, acc.w * s);
}

extern "C" void kernel_launch(void* const* d_in, const int* in_sizes, int n_in,
                              void* d_out, int out_size, void* d_ws, size_t ws_size,
                              hipStream_t stream) {
  const float* rp  = (const float*)d_in[0];
  const float* f0  = (const float*)d_in[1];
  const float* f1  = (const float*)d_in[2];
  const float* l2i = (const float*)d_in[3];
  float* out = (float*)d_out;

  const size_t n_elems = (size_t)6 * C_CH * 2816 + (size_t)6 * C_CH * 704;
  const size_t need = n_elems * sizeof(_Float16);

  if (ws_size >= need) {
    _Float16* ftp = (_Float16*)d_ws;
    transpose_both_f16<<<dim3(110, 4, 6), dim3(32, 8, 1), 0, stream>>>(f0, f1, ftp);
    bev_main_f16<<<dim3(4096), dim3(256), 0, stream>>>(rp, ftp, l2i, out);
  } else {
    bev_fallback<<<dim3(8192), dim3(256), 0, stream>>>(rp, f0, f1, l2i, out);
  }
}